// Round 1
// baseline (366.861 us; speedup 1.0000x reference)
//
#include <hip/hip_runtime.h>
#include <hip/hip_bf16.h>
#include <stdint.h>

typedef unsigned int uint;
typedef unsigned short ushort;

#define D 128
#define NEG_SLOPE 0.01f

using frag_t = __attribute__((ext_vector_type(8))) short;   // 8 bf16 in 4 VGPRs
using f32x4  = __attribute__((ext_vector_type(4))) float;

__device__ __forceinline__ ushort f2bf(float f) {
    __hip_bfloat16 b = __float2bfloat16(f);
    ushort u; __builtin_memcpy(&u, &b, 2); return u;
}
// bf16 pair unpack from packed uint (lo = element 0, hi = element 1)
__device__ __forceinline__ float bflo(uint p) { return __uint_as_float(p << 16); }
__device__ __forceinline__ float bfhi(uint p) { return __uint_as_float(p & 0xffff0000u); }

// ---------------------------------------------------------------------------
// K1: h = x @ W^T + b, stored as bf16.  Block = 256 thr (4 waves), tile 64x128.
// MFMA 16x16x32 bf16: A[m=lane&15][k=(lane>>4)*8+j], B[k=(lane>>4)*8+j][n=lane&15],
// C: col=lane&15, row=(lane>>4)*4+reg.
// ---------------------------------------------------------------------------
#define LDK 136   // 128 + 8 bf16 pad (16B) -> row starts 16B-aligned, conflicts <=2-way

__global__ __launch_bounds__(256) void gemm_h(
    const float* __restrict__ x, const float* __restrict__ W,
    const float* __restrict__ bias, ushort* __restrict__ h, int n)
{
    __shared__ ushort xs[64 * LDK];
    __shared__ ushort wsh[128 * LDK];
    const int tid  = threadIdx.x;
    const int row0 = blockIdx.x * 64;

    // stage x tile (64 rows) and full W (128 rows) as bf16
    {
        const int r = tid >> 5;          // 0..7
        const int k = (tid & 31) * 4;    // 0..124
#pragma unroll
        for (int i = 0; i < 8; ++i) {
            int lr = r + 8 * i;
            int gr = row0 + lr;
            int cr = gr < n ? gr : (n - 1);          // clamp; masked at store
            float4 v = *(const float4*)(x + (size_t)cr * D + k);
            ushort4 u; u.x = f2bf(v.x); u.y = f2bf(v.y); u.z = f2bf(v.z); u.w = f2bf(v.w);
            *(ushort4*)&xs[lr * LDK + k] = u;
        }
#pragma unroll
        for (int i = 0; i < 16; ++i) {
            int lr = r + 8 * i;
            float4 v = *(const float4*)(W + (size_t)lr * D + k);
            ushort4 u; u.x = f2bf(v.x); u.y = f2bf(v.y); u.z = f2bf(v.z); u.w = f2bf(v.w);
            *(ushort4*)&wsh[lr * LDK + k] = u;
        }
    }
    __syncthreads();

    const int wv   = tid >> 6;
    const int lane = tid & 63;
    const int mr   = lane & 15;
    const int qk   = (lane >> 4) * 8;

    f32x4 acc[8] = {};
    const ushort* xrow = xs + (16 * wv + mr) * LDK;
#pragma unroll
    for (int kk = 0; kk < 4; ++kk) {
        frag_t a = *(const frag_t*)(xrow + kk * 32 + qk);
#pragma unroll
        for (int t = 0; t < 8; ++t) {
            frag_t bf = *(const frag_t*)(wsh + (16 * t + mr) * LDK + kk * 32 + qk);
            acc[t] = __builtin_amdgcn_mfma_f32_16x16x32_bf16(a, bf, acc[t], 0, 0, 0);
        }
    }

    const int crow = 16 * wv + (lane >> 4) * 4;
#pragma unroll
    for (int t = 0; t < 8; ++t) {
        int col = 16 * t + mr;
        float bb = bias[col];
#pragma unroll
        for (int r = 0; r < 4; ++r) {
            int grow = row0 + crow + r;
            if (grow < n) h[(size_t)grow * D + col] = f2bf(acc[t][r] + bb);
        }
    }
}

// ---------------------------------------------------------------------------
// K2: per-node attention scalars  s_i[n] = h[n]·a_i + b_att,  s_j[n] = h[n]·a_j
// One wave per node, 2 cols per lane, butterfly reduce.
// ---------------------------------------------------------------------------
__global__ __launch_bounds__(256) void node_scores(
    const ushort* __restrict__ h, const float* __restrict__ Wa,
    const float* __restrict__ ba, float* __restrict__ si, float* __restrict__ sj, int n)
{
    int node = blockIdx.x * 4 + (threadIdx.x >> 6);
    if (node >= n) return;
    int lane = threadIdx.x & 63;
    uint hv = *(const uint*)(h + (size_t)node * D + lane * 2);
    float h0 = bflo(hv), h1 = bfhi(hv);
    float pi = h0 * Wa[2 * lane]     + h1 * Wa[2 * lane + 1];
    float pj = h0 * Wa[D + 2 * lane] + h1 * Wa[D + 2 * lane + 1];
#pragma unroll
    for (int o = 32; o; o >>= 1) { pi += __shfl_xor(pi, o); pj += __shfl_xor(pj, o); }
    if (lane == 0) { si[node] = pi + ba[0]; sj[node] = pj; }
}

// ---------------------------------------------------------------------------
// K3..K6: CSR build (count / scan / fill) then per-node aggregation
// ---------------------------------------------------------------------------
__global__ void count_k(const int* __restrict__ src, int* __restrict__ cnt, int e) {
    int i = blockIdx.x * 256 + threadIdx.x;
    if (i < e) atomicAdd(&cnt[src[i]], 1);
}

__global__ void scan_block(const int* __restrict__ cnt, int* __restrict__ ofs,
                           int* __restrict__ bsum, int n) {
    __shared__ int s[256];
    int t = threadIdx.x;
    int i = blockIdx.x * 256 + t;
    int v = (i < n) ? cnt[i] : 0;
    s[t] = v; __syncthreads();
#pragma unroll
    for (int o = 1; o < 256; o <<= 1) {
        int tv = (t >= o) ? s[t - o] : 0;
        __syncthreads();
        s[t] += tv;
        __syncthreads();
    }
    if (i < n) ofs[i] = s[t] - v;              // chunk-local exclusive
    if (t == 255) bsum[blockIdx.x] = s[255];   // chunk total
}

__global__ void scan_top(int* __restrict__ bsum, int nb) {
    __shared__ int s[512];
    int t = threadIdx.x;
    int v = (t < nb) ? bsum[t] : 0;
    s[t] = v; __syncthreads();
#pragma unroll
    for (int o = 1; o < 512; o <<= 1) {
        int tv = (t >= o) ? s[t - o] : 0;
        __syncthreads();
        s[t] += tv;
        __syncthreads();
    }
    if (t < nb) bsum[t] = s[t] - v;            // exclusive block offsets
}

__global__ void scan_add(int* __restrict__ ofs, const int* __restrict__ bsum,
                         int* __restrict__ cursor, int n) {
    int i = blockIdx.x * 256 + threadIdx.x;
    if (i < n) {
        int v = ofs[i] + bsum[i >> 8];
        ofs[i] = v;
        cursor[i] = v;
    }
}

__global__ void fill_k(const int* __restrict__ src, const int* __restrict__ dst,
                       const float* __restrict__ si, const float* __restrict__ sj,
                       int* __restrict__ cursor, int2* __restrict__ edata, int e) {
    int i = blockIdx.x * 256 + threadIdx.x;
    if (i < e) {
        int s = src[i], d = dst[i];
        float sc = si[s] + sj[d];
        sc = sc >= 0.f ? sc : NEG_SLOPE * sc;
        float w = expf(sc);
        int p = atomicAdd(&cursor[s], 1);
        edata[p] = make_int2(d, __float_as_int(w));
    }
}

// one wave per node: gather h[dst] rows (256B coalesced), accumulate in regs
__global__ __launch_bounds__(256) void agg_k(
    const ushort* __restrict__ h, const int2* __restrict__ edata,
    const int* __restrict__ ofs, const int* __restrict__ cnt,
    const float* __restrict__ si, const float* __restrict__ sj,
    float* __restrict__ out, int n)
{
    int node = blockIdx.x * 4 + (threadIdx.x >> 6);
    if (node >= n) return;
    int lane = threadIdx.x & 63;

    // self-loop
    float sc = si[node] + sj[node];
    sc = sc >= 0.f ? sc : NEG_SLOPE * sc;
    float w = expf(sc);
    uint hv = *(const uint*)(h + (size_t)node * D + lane * 2);
    float a0 = w * bflo(hv), a1 = w * bfhi(hv);
    float denom = w;

    const int2* ed = edata + ofs[node];
    int num = cnt[node];
    int i = 0;
    for (; i + 4 <= num; i += 4) {          // 4-way ILP on the gather chain
        int2 r0 = ed[i], r1 = ed[i + 1], r2 = ed[i + 2], r3 = ed[i + 3];
        uint g0 = *(const uint*)(h + (size_t)r0.x * D + lane * 2);
        uint g1 = *(const uint*)(h + (size_t)r1.x * D + lane * 2);
        uint g2 = *(const uint*)(h + (size_t)r2.x * D + lane * 2);
        uint g3 = *(const uint*)(h + (size_t)r3.x * D + lane * 2);
        float w0 = __int_as_float(r0.y), w1 = __int_as_float(r1.y);
        float w2 = __int_as_float(r2.y), w3 = __int_as_float(r3.y);
        denom += (w0 + w1) + (w2 + w3);
        a0 += w0 * bflo(g0) + w1 * bflo(g1) + w2 * bflo(g2) + w3 * bflo(g3);
        a1 += w0 * bfhi(g0) + w1 * bfhi(g1) + w2 * bfhi(g2) + w3 * bfhi(g3);
    }
    for (; i < num; ++i) {
        int2 r = ed[i];
        uint g = *(const uint*)(h + (size_t)r.x * D + lane * 2);
        float we = __int_as_float(r.y);
        denom += we;
        a0 += we * bflo(g);
        a1 += we * bfhi(g);
    }

    float inv = 1.f / denom;
    a0 *= inv; a1 *= inv;
    a0 = a0 > 0.f ? a0 : expm1f(a0);        // ELU (alpha=1)
    a1 = a1 > 0.f ? a1 : expm1f(a1);
    *(float2*)(out + (size_t)node * D + lane * 2) = make_float2(a0, a1);
}

// ---------------------------------------------------------------------------
extern "C" void kernel_launch(void* const* d_in, const int* in_sizes, int n_in,
                              void* d_out, int out_size, void* d_ws, size_t ws_size,
                              hipStream_t stream)
{
    const float* x  = (const float*)d_in[0];
    const int*   ei = (const int*)  d_in[1];
    const float* Wl = (const float*)d_in[2];
    const float* bl = (const float*)d_in[3];
    const float* Wa = (const float*)d_in[4];
    const float* ba = (const float*)d_in[5];
    const int n = in_sizes[0] / D;
    const int e = in_sizes[1] / 2;
    const int* src = ei;
    const int* dst = ei + e;

    // workspace carve-up (all 16B-aligned)
    char* w = (char*)d_ws;
    size_t off = 0;
    ushort* h      = (ushort*)(w + off); off += (size_t)n * D * 2;   // 25.6 MB
    float*  si     = (float*) (w + off); off += (size_t)n * 4;
    float*  sj     = (float*) (w + off); off += (size_t)n * 4;
    int*    cnt    = (int*)   (w + off); off += (size_t)n * 4;
    int*    ofs    = (int*)   (w + off); off += (size_t)n * 4;
    int*    cursor = (int*)   (w + off); off += (size_t)n * 4;
    int*    bsum   = (int*)   (w + off); off += 512 * 4;
    int2*   edata  = (int2*)  (w + off); off += (size_t)e * 8;       // 12.8 MB

    const int nb = (n + 255) / 256;   // 391 <= 512

    gemm_h     <<<(n + 63) / 64,  256, 0, stream>>>(x, Wl, bl, h, n);
    node_scores<<<(n + 3) / 4,    256, 0, stream>>>(h, Wa, ba, si, sj, n);
    hipMemsetAsync(cnt, 0, (size_t)n * 4, stream);
    count_k    <<<(e + 255) / 256, 256, 0, stream>>>(src, cnt, e);
    scan_block <<<nb,             256, 0, stream>>>(cnt, ofs, bsum, n);
    scan_top   <<<1,              512, 0, stream>>>(bsum, nb);
    scan_add   <<<nb,             256, 0, stream>>>(ofs, bsum, cursor, n);
    fill_k     <<<(e + 255) / 256, 256, 0, stream>>>(src, dst, si, sj, cursor, edata, e);
    agg_k      <<<(n + 3) / 4,    256, 0, stream>>>(h, edata, ofs, cnt, si, sj, (float*)d_out, n);
}